// Round 2
// 441.103 us; speedup vs baseline: 1.0608x; 1.0608x over previous
//
#include <hip/hip_runtime.h>
#include <math.h>

#define B_ 4
#define N_ 1024
#define C_ 512
#define H_ 8
#define HD_ 64
#define SCALE_ 0.125f
#define LN_EPS_ 1e-5f

typedef _Float16 f16x8 __attribute__((ext_vector_type(8)));
typedef float f32x4 __attribute__((ext_vector_type(4)));

// Split 8 fp32 (two float4) into f16 hi + f16 lo such that hi+lo ~= x (22-bit).
__device__ __forceinline__ void cvt_split(const float4& A, const float4& Bv,
                                          f16x8& hi, f16x8& lo) {
    float v[8] = {A.x, A.y, A.z, A.w, Bv.x, Bv.y, Bv.z, Bv.w};
#pragma unroll
    for (int i = 0; i < 8; ++i) {
        _Float16 h = (_Float16)v[i];
        hi[i] = h;
        lo[i] = (_Float16)(v[i] - (float)h);
    }
}

// ---------------------------------------------------------------------------
// Kernel 1: qkv = x @ Wqkv + bqkv   (unchanged)
// ---------------------------------------------------------------------------
__global__ __launch_bounds__(256) void qkv_gemm(const float* __restrict__ x,
                                                const float* __restrict__ Wqkv,
                                                const float* __restrict__ bqkv,
                                                float* __restrict__ qkv) {
    const int K = C_;        // 512
    const int NN = 3 * C_;   // 1536
    __shared__ float As[64][17];
    __shared__ float Bs[16][64];

    const int tid = threadIdx.x;
    const int tx = tid & 15;
    const int ty = tid >> 4;
    const int row0 = blockIdx.y * 64;
    const int col0 = blockIdx.x * 64;

    float acc[4][4] = {};

    for (int kt = 0; kt < K; kt += 16) {
        {
            int lin = tid * 4;
            int m = lin >> 4;
            int k = lin & 15;
            float4 a = *(const float4*)&x[(size_t)(row0 + m) * K + kt + k];
            As[m][k + 0] = a.x; As[m][k + 1] = a.y;
            As[m][k + 2] = a.z; As[m][k + 3] = a.w;
        }
        {
            int lin = tid * 4;
            int kk = lin >> 6;
            int n = lin & 63;
            *(float4*)&Bs[kk][n] =
                *(const float4*)&Wqkv[(size_t)(kt + kk) * NN + col0 + n];
        }
        __syncthreads();
#pragma unroll
        for (int kk = 0; kk < 16; ++kk) {
            float a[4], bb[4];
#pragma unroll
            for (int i = 0; i < 4; ++i) a[i] = As[ty * 4 + i][kk];
#pragma unroll
            for (int j = 0; j < 4; ++j) bb[j] = Bs[kk][tx * 4 + j];
#pragma unroll
            for (int i = 0; i < 4; ++i)
#pragma unroll
                for (int j = 0; j < 4; ++j) acc[i][j] += a[i] * bb[j];
        }
        __syncthreads();
    }
#pragma unroll
    for (int i = 0; i < 4; ++i) {
        int r = row0 + ty * 4 + i;
        int c = col0 + tx * 4;
        float4 o;
        o.x = acc[i][0] + bqkv[c + 0];
        o.y = acc[i][1] + bqkv[c + 1];
        o.z = acc[i][2] + bqkv[c + 2];
        o.w = acc[i][3] + bqkv[c + 3];
        *(float4*)&qkv[(size_t)r * NN + c] = o;
    }
}

// ---------------------------------------------------------------------------
// Kernel 2: attn_scores — MFMA f16-split QK^T + polynomial + softmax.
//   Block: 16 query rows of one (b,h); 4 waves, each owning 256 key-cols.
//   fp32 emulated as hi*hi + hi*lo + lo*hi (3 MFMA passes, ~22-bit mantissa).
//   MFMA 16x16x32 layouts: A row=lane&15, k=8*(lane>>4)+j (contiguous);
//   B col=lane&15, same k; D col=lane&15, row=4*(lane>>4)+reg.
// ---------------------------------------------------------------------------
__global__ __launch_bounds__(256) void attn_scores(const float* __restrict__ qkv,
                                                   const float* __restrict__ ow_in,
                                                   float* __restrict__ attn) {
    __shared__ float smax[4][16];
    __shared__ float ssum[4][16];

    const int tid = threadIdx.x;
    const int lane = tid & 63;
    const int w = tid >> 6;           // wave 0..3 -> key cols [w*256, w*256+256)
    const int r16 = lane & 15;        // A row / B col / D col
    const int g = lane >> 4;          // k-group: k = 8g..8g+7 (+32 for kstep1)
    const int n0 = blockIdx.x * 16;   // query-row tile
    const int bh = blockIdx.y;
    const int b = bh >> 3, h = bh & 7;
    const size_t RS = 3 * C_;

    // order-weights softmax (broadcast scalar work)
    float w0 = ow_in[0], w1 = ow_in[1], w2 = ow_in[2];
    float wm = fmaxf(w0, fmaxf(w1, w2));
    float e0 = __expf(w0 - wm), e1 = __expf(w1 - wm), e2 = __expf(w2 - wm);
    float einv = 1.0f / (e0 + e1 + e2);
    float ow0 = e0 * einv, ow1 = e1 * einv, ow2 = e2 * einv;

    // ---- A fragments: Q[16][64] -> f16 hi/lo, held in regs for all tiles ----
    const float* qrow = qkv + (size_t)(b * N_ + n0 + r16) * RS + h * HD_;
    f16x8 aHi0, aLo0, aHi1, aLo1;
    {
        float4 qa = ((const float4*)qrow)[2 * g + 0];
        float4 qb = ((const float4*)qrow)[2 * g + 1];
        float4 qc = ((const float4*)qrow)[8 + 2 * g];
        float4 qd = ((const float4*)qrow)[9 + 2 * g];
        cvt_split(qa, qb, aHi0, aLo0);
        cvt_split(qc, qd, aHi1, aLo1);
    }

    float p[16][4];   // logits (later probabilities): p[t][j] = row 4g+j, col w*256+t*16+r16

    const float* kbase = qkv + (size_t)(b * N_) * RS + C_ + h * HD_;
#pragma unroll
    for (int t = 0; t < 16; ++t) {
        const int ct = w * 16 + t;
        const float* krow = kbase + (size_t)(ct * 16 + r16) * RS;
        float4 ka = ((const float4*)krow)[2 * g + 0];
        float4 kb = ((const float4*)krow)[2 * g + 1];
        float4 kc = ((const float4*)krow)[8 + 2 * g];
        float4 kd = ((const float4*)krow)[9 + 2 * g];
        f16x8 bHi0, bLo0, bHi1, bLo1;
        cvt_split(ka, kb, bHi0, bLo0);
        cvt_split(kc, kd, bHi1, bLo1);

        f32x4 acc = {0.f, 0.f, 0.f, 0.f};
        acc = __builtin_amdgcn_mfma_f32_16x16x32_f16(aHi0, bHi0, acc, 0, 0, 0);
        acc = __builtin_amdgcn_mfma_f32_16x16x32_f16(aHi0, bLo0, acc, 0, 0, 0);
        acc = __builtin_amdgcn_mfma_f32_16x16x32_f16(aLo0, bHi0, acc, 0, 0, 0);
        acc = __builtin_amdgcn_mfma_f32_16x16x32_f16(aHi1, bHi1, acc, 0, 0, 0);
        acc = __builtin_amdgcn_mfma_f32_16x16x32_f16(aHi1, bLo1, acc, 0, 0, 0);
        acc = __builtin_amdgcn_mfma_f32_16x16x32_f16(aLo1, bHi1, acc, 0, 0, 0);

#pragma unroll
        for (int j = 0; j < 4; ++j) {
            float s = acc[j] * SCALE_;
            p[t][j] = s * (ow0 + s * (ow1 + s * ow2));
        }
    }

    // ---- row max: lane-local, then 16-lane group reduce, then cross-wave ----
    float rmax[4] = {-1e30f, -1e30f, -1e30f, -1e30f};
#pragma unroll
    for (int t = 0; t < 16; ++t)
#pragma unroll
        for (int j = 0; j < 4; ++j) rmax[j] = fmaxf(rmax[j], p[t][j]);
#pragma unroll
    for (int j = 0; j < 4; ++j)
#pragma unroll
        for (int m = 1; m < 16; m <<= 1)
            rmax[j] = fmaxf(rmax[j], __shfl_xor(rmax[j], m, 64));
    if (r16 == 0) {
#pragma unroll
        for (int j = 0; j < 4; ++j) smax[w][g * 4 + j] = rmax[j];
    }
    __syncthreads();
    float gm[4];
#pragma unroll
    for (int j = 0; j < 4; ++j) {
        int rr = g * 4 + j;
        gm[j] = fmaxf(fmaxf(smax[0][rr], smax[1][rr]),
                      fmaxf(smax[2][rr], smax[3][rr]));
    }

    // ---- exp + row sum ----
    float rsum[4] = {0.f, 0.f, 0.f, 0.f};
#pragma unroll
    for (int t = 0; t < 16; ++t)
#pragma unroll
        for (int j = 0; j < 4; ++j) {
            float e = __expf(p[t][j] - gm[j]);
            p[t][j] = e;
            rsum[j] += e;
        }
#pragma unroll
    for (int j = 0; j < 4; ++j)
#pragma unroll
        for (int m = 1; m < 16; m <<= 1)
            rsum[j] += __shfl_xor(rsum[j], m, 64);
    if (r16 == 0) {
#pragma unroll
        for (int j = 0; j < 4; ++j) ssum[w][g * 4 + j] = rsum[j];
    }
    __syncthreads();
    float inv[4];
#pragma unroll
    for (int j = 0; j < 4; ++j) {
        int rr = g * 4 + j;
        inv[j] = 1.0f / (ssum[0][rr] + ssum[1][rr] + ssum[2][rr] + ssum[3][rr]);
    }

    // ---- normalize + store ----
    float* abase = attn + ((size_t)bh * N_ + n0 + 4 * g) * N_ + w * 256 + r16;
#pragma unroll
    for (int j = 0; j < 4; ++j) {
        float* arow = abase + (size_t)j * N_;
        float sc = inv[j];
#pragma unroll
        for (int t = 0; t < 16; ++t)
            arow[t * 16] = p[t][j] * sc;
    }
}

// ---------------------------------------------------------------------------
// Kernel 3: pv_gemm (unchanged)
// ---------------------------------------------------------------------------
__global__ __launch_bounds__(256) void pv_gemm(const float* __restrict__ qkv,
                                               const float* __restrict__ attn,
                                               float* __restrict__ ctx) {
    __shared__ __align__(16) float Pst[64][68];   // [m][n]  (transposed P)
    __shared__ __align__(16) float Vs[64][68];    // [m][d]

    const int tid = threadIdx.x;
    const int tx = tid & 15;          // d-group
    const int ty = tid >> 4;          // n-group
    const int n0 = blockIdx.x * 64;
    const int bh = blockIdx.y;
    const int b = bh >> 3, h = bh & 7;
    const size_t RS = 3 * C_;

    const int rr = tid >> 2;          // staging row 0..63
    const int q = tid & 3;            // staging quarter

    float acc[4][4] = {};

    for (int mt = 0; mt < 16; ++mt) {
        const int m0 = mt * 64;
        const float* prow = attn + ((size_t)bh * N_ + n0 + rr) * N_ + m0 + q * 16;
        const float* vrow = qkv + (size_t)(b * N_ + m0 + rr) * RS + 2 * C_ + h * HD_ + q * 16;
        float4 pv[4], vv[4];
#pragma unroll
        for (int m = 0; m < 4; ++m) pv[m] = ((const float4*)prow)[m];
#pragma unroll
        for (int m = 0; m < 4; ++m) vv[m] = ((const float4*)vrow)[m];
        __syncthreads();
#pragma unroll
        for (int m = 0; m < 4; ++m) {
            int c = q * 16 + m * 4;
            Pst[c + 0][rr] = pv[m].x; Pst[c + 1][rr] = pv[m].y;
            Pst[c + 2][rr] = pv[m].z; Pst[c + 3][rr] = pv[m].w;
            *(float4*)&Vs[rr][c] = vv[m];
        }
        __syncthreads();
#pragma unroll 16
        for (int mm = 0; mm < 64; ++mm) {
            float4 a4 = *(const float4*)&Pst[mm][ty * 4];
            float4 b4 = *(const float4*)&Vs[mm][tx * 4];
            float a[4] = {a4.x, a4.y, a4.z, a4.w};
            float bb[4] = {b4.x, b4.y, b4.z, b4.w};
#pragma unroll
            for (int i = 0; i < 4; ++i)
#pragma unroll
                for (int j = 0; j < 4; ++j) acc[i][j] += a[i] * bb[j];
        }
    }
#pragma unroll
    for (int i = 0; i < 4; ++i) {
        float4 o;
        o.x = acc[i][0]; o.y = acc[i][1]; o.z = acc[i][2]; o.w = acc[i][3];
        *(float4*)&ctx[(size_t)(b * N_ + n0 + ty * 4 + i) * C_ + h * HD_ + tx * 4] = o;
    }
}

// ---------------------------------------------------------------------------
// Kernel 4: proj_gemm — y_pre = ctx @ Wproj + bproj + x  (unchanged)
// ---------------------------------------------------------------------------
__global__ __launch_bounds__(256) void proj_gemm(const float* __restrict__ ctx,
                                                 const float* __restrict__ x,
                                                 const float* __restrict__ Wproj,
                                                 const float* __restrict__ bproj,
                                                 float* __restrict__ y) {
    const int K = C_;
    const int NN = C_;
    __shared__ float As[64][17];
    __shared__ float Bs[16][64];

    const int tid = threadIdx.x;
    const int tx = tid & 15;
    const int ty = tid >> 4;
    const int row0 = blockIdx.y * 64;
    const int col0 = blockIdx.x * 64;

    float acc[4][4] = {};

    for (int kt = 0; kt < K; kt += 16) {
        {
            int lin = tid * 4;
            int m = lin >> 4;
            int k = lin & 15;
            float4 a = *(const float4*)&ctx[(size_t)(row0 + m) * K + kt + k];
            As[m][k + 0] = a.x; As[m][k + 1] = a.y;
            As[m][k + 2] = a.z; As[m][k + 3] = a.w;
        }
        {
            int lin = tid * 4;
            int kk = lin >> 6;
            int n = lin & 63;
            *(float4*)&Bs[kk][n] =
                *(const float4*)&Wproj[(size_t)(kt + kk) * NN + col0 + n];
        }
        __syncthreads();
#pragma unroll
        for (int kk = 0; kk < 16; ++kk) {
            float a[4], bb[4];
#pragma unroll
            for (int i = 0; i < 4; ++i) a[i] = As[ty * 4 + i][kk];
#pragma unroll
            for (int j = 0; j < 4; ++j) bb[j] = Bs[kk][tx * 4 + j];
#pragma unroll
            for (int i = 0; i < 4; ++i)
#pragma unroll
                for (int j = 0; j < 4; ++j) acc[i][j] += a[i] * bb[j];
        }
        __syncthreads();
    }
#pragma unroll
    for (int i = 0; i < 4; ++i) {
        int r = row0 + ty * 4 + i;
        int c = col0 + tx * 4;
        float4 xr = *(const float4*)&x[(size_t)r * C_ + c];
        float4 o;
        o.x = acc[i][0] + bproj[c + 0] + xr.x;
        o.y = acc[i][1] + bproj[c + 1] + xr.y;
        o.z = acc[i][2] + bproj[c + 2] + xr.z;
        o.w = acc[i][3] + bproj[c + 3] + xr.w;
        *(float4*)&y[(size_t)r * C_ + c] = o;
    }
}

// ---------------------------------------------------------------------------
// Kernel 5: ln_kernel (unchanged)
// ---------------------------------------------------------------------------
__global__ __launch_bounds__(256) void ln_kernel(float* __restrict__ y,
                                                 const float* __restrict__ gamma,
                                                 const float* __restrict__ beta) {
    __shared__ float wsum[4], wsq[4];
    const int row = blockIdx.x;
    const int tid = threadIdx.x;
    const int lane = tid & 63;
    const int w = tid >> 6;

    float2 v = ((const float2*)(y + (size_t)row * C_))[tid];
    float s = v.x + v.y;
    float sq = v.x * v.x + v.y * v.y;
#pragma unroll
    for (int m = 1; m < 64; m <<= 1) {
        s += __shfl_xor(s, m, 64);
        sq += __shfl_xor(sq, m, 64);
    }
    if (lane == 0) { wsum[w] = s; wsq[w] = sq; }
    __syncthreads();
    float ts = wsum[0] + wsum[1] + wsum[2] + wsum[3];
    float tq = wsq[0] + wsq[1] + wsq[2] + wsq[3];
    float mu = ts * (1.0f / C_);
    float var = tq * (1.0f / C_) - mu * mu;
    float rstd = rsqrtf(var + LN_EPS_);

    float2 g = ((const float2*)gamma)[tid];
    float2 be = ((const float2*)beta)[tid];
    float2 o;
    o.x = (v.x - mu) * rstd * g.x + be.x;
    o.y = (v.y - mu) * rstd * g.y + be.y;
    ((float2*)(y + (size_t)row * C_))[tid] = o;
}

extern "C" void kernel_launch(void* const* d_in, const int* in_sizes, int n_in,
                              void* d_out, int out_size, void* d_ws, size_t ws_size,
                              hipStream_t stream) {
    const float* x     = (const float*)d_in[0];
    const float* Wqkv  = (const float*)d_in[1];
    const float* bqkv  = (const float*)d_in[2];
    const float* ow    = (const float*)d_in[3];
    const float* Wproj = (const float*)d_in[4];
    const float* bproj = (const float*)d_in[5];
    const float* gamma = (const float*)d_in[6];
    const float* beta  = (const float*)d_in[7];

    float* out  = (float*)d_out;
    float* y    = out;                                  // [B,N,C]
    float* attn = out + (size_t)B_ * N_ * C_;           // [B,H,N,N]
    float* qkv  = (float*)d_ws;                         // [B*N, 3C]  25 MB
    float* ctx  = qkv + (size_t)B_ * N_ * 3 * C_;       // [B*N, C]    8 MB

    dim3 g1(3 * C_ / 64, B_ * N_ / 64);                 // (24, 64)
    qkv_gemm<<<g1, 256, 0, stream>>>(x, Wqkv, bqkv, qkv);

    dim3 g2(N_ / 16, B_ * H_);                          // (64, 32)
    attn_scores<<<g2, 256, 0, stream>>>(qkv, ow, attn);

    dim3 g3(N_ / 64, B_ * H_);                          // (16, 32)
    pv_gemm<<<g3, 256, 0, stream>>>(qkv, attn, ctx);

    dim3 g4(C_ / 64, B_ * N_ / 64);                     // (8, 64)
    proj_gemm<<<g4, 256, 0, stream>>>(ctx, x, Wproj, bproj, y);

    ln_kernel<<<B_ * N_, 256, 0, stream>>>(y, gamma, beta);
}

// Round 3
// 417.389 us; speedup vs baseline: 1.1211x; 1.0568x over previous
//
#include <hip/hip_runtime.h>
#include <math.h>

#define B_ 4
#define N_ 1024
#define C_ 512
#define H_ 8
#define HD_ 64
#define SCALE_ 0.125f
#define LN_EPS_ 1e-5f

typedef _Float16 f16x8 __attribute__((ext_vector_type(8)));
typedef float f32x4 __attribute__((ext_vector_type(4)));

// Split 8 fp32 (two float4) into f16 hi + f16 lo such that hi+lo ~= x (22-bit).
__device__ __forceinline__ void cvt_split(const float4& A, const float4& Bv,
                                          f16x8& hi, f16x8& lo) {
    float v[8] = {A.x, A.y, A.z, A.w, Bv.x, Bv.y, Bv.z, Bv.w};
#pragma unroll
    for (int i = 0; i < 8; ++i) {
        _Float16 h = (_Float16)v[i];
        hi[i] = h;
        lo[i] = (_Float16)(v[i] - (float)h);
    }
}

// ---------------------------------------------------------------------------
// Kernel 0: wsplit_qkv — transpose + f16-split Wqkv [512][1536] into
//   Wt_hi/Wt_lo [1536][512] (row = output column, k contiguous).
//   Output lives in the attn region (rewritten later by attn_scores).
// ---------------------------------------------------------------------------
__global__ __launch_bounds__(256) void wsplit_qkv(const float* __restrict__ W,
                                                  _Float16* __restrict__ wt_hi,
                                                  _Float16* __restrict__ wt_lo) {
    __shared__ float tile[64][65];
    const int tid = threadIdx.x;
    const int n0 = blockIdx.x * 64;   // col of W  (row of Wt)
    const int k0 = blockIdx.y * 64;   // row of W  (col of Wt)
#pragma unroll
    for (int i = 0; i < 16; ++i) {
        int e = tid + i * 256;
        int kk = e >> 6, nn = e & 63;
        tile[kk][nn] = W[(size_t)(k0 + kk) * (3 * C_) + n0 + nn];
    }
    __syncthreads();
#pragma unroll
    for (int i = 0; i < 16; ++i) {
        int e = tid + i * 256;
        int n = e >> 6, k = e & 63;
        float v = tile[k][n];
        _Float16 h = (_Float16)v;
        wt_hi[(size_t)(n0 + n) * C_ + k0 + k] = h;
        wt_lo[(size_t)(n0 + n) * C_ + k0 + k] = (_Float16)(v - (float)h);
    }
}

// ---------------------------------------------------------------------------
// Kernel 1: qkv_gemm_mfma — qkv = x @ Wqkv + bqkv via f16-split MFMA.
//   Block: 32 rows x 256 cols, 4 waves; wave = 2 row-tiles x 4 col-tiles.
//   A (x) split on the fly; B read pre-split from Wt (k-contiguous f16x8).
// ---------------------------------------------------------------------------
__global__ __launch_bounds__(256) void qkv_gemm_mfma(const float* __restrict__ x,
                                                     const _Float16* __restrict__ wt_hi,
                                                     const _Float16* __restrict__ wt_lo,
                                                     const float* __restrict__ bqkv,
                                                     float* __restrict__ qkv) {
    const int tid = threadIdx.x;
    const int lane = tid & 63;
    const int w = tid >> 6;
    const int r16 = lane & 15;
    const int g = lane >> 4;
    const int row0 = blockIdx.x * 32;
    const int col0 = blockIdx.y * 256 + w * 64;

    f32x4 acc[2][4] = {};

    const float* xr0 = x + (size_t)(row0 + r16) * C_;
    const float* xr1 = x + (size_t)(row0 + 16 + r16) * C_;

    for (int kt = 0; kt < 16; ++kt) {
        const int k0 = kt * 32 + 8 * g;
        f16x8 aHi0, aLo0, aHi1, aLo1;
        {
            float4 a0 = *(const float4*)&xr0[k0];
            float4 a1 = *(const float4*)&xr0[k0 + 4];
            cvt_split(a0, a1, aHi0, aLo0);
            float4 b0 = *(const float4*)&xr1[k0];
            float4 b1 = *(const float4*)&xr1[k0 + 4];
            cvt_split(b0, b1, aHi1, aLo1);
        }
#pragma unroll
        for (int ct = 0; ct < 4; ++ct) {
            const int c = col0 + ct * 16 + r16;
            f16x8 bHi = *(const f16x8*)&wt_hi[(size_t)c * C_ + k0];
            f16x8 bLo = *(const f16x8*)&wt_lo[(size_t)c * C_ + k0];
            acc[0][ct] = __builtin_amdgcn_mfma_f32_16x16x32_f16(aHi0, bHi, acc[0][ct], 0, 0, 0);
            acc[0][ct] = __builtin_amdgcn_mfma_f32_16x16x32_f16(aHi0, bLo, acc[0][ct], 0, 0, 0);
            acc[0][ct] = __builtin_amdgcn_mfma_f32_16x16x32_f16(aLo0, bHi, acc[0][ct], 0, 0, 0);
            acc[1][ct] = __builtin_amdgcn_mfma_f32_16x16x32_f16(aHi1, bHi, acc[1][ct], 0, 0, 0);
            acc[1][ct] = __builtin_amdgcn_mfma_f32_16x16x32_f16(aHi1, bLo, acc[1][ct], 0, 0, 0);
            acc[1][ct] = __builtin_amdgcn_mfma_f32_16x16x32_f16(aLo1, bHi, acc[1][ct], 0, 0, 0);
        }
    }

#pragma unroll
    for (int rt = 0; rt < 2; ++rt)
#pragma unroll
        for (int ct = 0; ct < 4; ++ct) {
            const int c = col0 + ct * 16 + r16;
            const float bias = bqkv[c];
#pragma unroll
            for (int j = 0; j < 4; ++j) {
                const int r = row0 + rt * 16 + 4 * g + j;
                qkv[(size_t)r * (3 * C_) + c] = acc[rt][ct][j] + bias;
            }
        }
}

// ---------------------------------------------------------------------------
// Kernel 2: attn_scores — MFMA f16-split QK^T + polynomial + softmax.
//   (unchanged — validated round 2)
// ---------------------------------------------------------------------------
__global__ __launch_bounds__(256) void attn_scores(const float* __restrict__ qkv,
                                                   const float* __restrict__ ow_in,
                                                   float* __restrict__ attn) {
    __shared__ float smax[4][16];
    __shared__ float ssum[4][16];

    const int tid = threadIdx.x;
    const int lane = tid & 63;
    const int w = tid >> 6;           // wave 0..3 -> key cols [w*256, w*256+256)
    const int r16 = lane & 15;        // A row / B col / D col
    const int g = lane >> 4;          // k-group: k = 8g..8g+7 (+32 for kstep1)
    const int n0 = blockIdx.x * 16;   // query-row tile
    const int bh = blockIdx.y;
    const int b = bh >> 3, h = bh & 7;
    const size_t RS = 3 * C_;

    float w0 = ow_in[0], w1 = ow_in[1], w2 = ow_in[2];
    float wm = fmaxf(w0, fmaxf(w1, w2));
    float e0 = __expf(w0 - wm), e1 = __expf(w1 - wm), e2 = __expf(w2 - wm);
    float einv = 1.0f / (e0 + e1 + e2);
    float ow0 = e0 * einv, ow1 = e1 * einv, ow2 = e2 * einv;

    const float* qrow = qkv + (size_t)(b * N_ + n0 + r16) * RS + h * HD_;
    f16x8 aHi0, aLo0, aHi1, aLo1;
    {
        float4 qa = ((const float4*)qrow)[2 * g + 0];
        float4 qb = ((const float4*)qrow)[2 * g + 1];
        float4 qc = ((const float4*)qrow)[8 + 2 * g];
        float4 qd = ((const float4*)qrow)[9 + 2 * g];
        cvt_split(qa, qb, aHi0, aLo0);
        cvt_split(qc, qd, aHi1, aLo1);
    }

    float p[16][4];

    const float* kbase = qkv + (size_t)(b * N_) * RS + C_ + h * HD_;
#pragma unroll
    for (int t = 0; t < 16; ++t) {
        const int ct = w * 16 + t;
        const float* krow = kbase + (size_t)(ct * 16 + r16) * RS;
        float4 ka = ((const float4*)krow)[2 * g + 0];
        float4 kb = ((const float4*)krow)[2 * g + 1];
        float4 kc = ((const float4*)krow)[8 + 2 * g];
        float4 kd = ((const float4*)krow)[9 + 2 * g];
        f16x8 bHi0, bLo0, bHi1, bLo1;
        cvt_split(ka, kb, bHi0, bLo0);
        cvt_split(kc, kd, bHi1, bLo1);

        f32x4 acc = {0.f, 0.f, 0.f, 0.f};
        acc = __builtin_amdgcn_mfma_f32_16x16x32_f16(aHi0, bHi0, acc, 0, 0, 0);
        acc = __builtin_amdgcn_mfma_f32_16x16x32_f16(aHi0, bLo0, acc, 0, 0, 0);
        acc = __builtin_amdgcn_mfma_f32_16x16x32_f16(aLo0, bHi0, acc, 0, 0, 0);
        acc = __builtin_amdgcn_mfma_f32_16x16x32_f16(aHi1, bHi1, acc, 0, 0, 0);
        acc = __builtin_amdgcn_mfma_f32_16x16x32_f16(aHi1, bLo1, acc, 0, 0, 0);
        acc = __builtin_amdgcn_mfma_f32_16x16x32_f16(aLo1, bHi1, acc, 0, 0, 0);

#pragma unroll
        for (int j = 0; j < 4; ++j) {
            float s = acc[j] * SCALE_;
            p[t][j] = s * (ow0 + s * (ow1 + s * ow2));
        }
    }

    float rmax[4] = {-1e30f, -1e30f, -1e30f, -1e30f};
#pragma unroll
    for (int t = 0; t < 16; ++t)
#pragma unroll
        for (int j = 0; j < 4; ++j) rmax[j] = fmaxf(rmax[j], p[t][j]);
#pragma unroll
    for (int j = 0; j < 4; ++j)
#pragma unroll
        for (int m = 1; m < 16; m <<= 1)
            rmax[j] = fmaxf(rmax[j], __shfl_xor(rmax[j], m, 64));
    if (r16 == 0) {
#pragma unroll
        for (int j = 0; j < 4; ++j) smax[w][g * 4 + j] = rmax[j];
    }
    __syncthreads();
    float gm[4];
#pragma unroll
    for (int j = 0; j < 4; ++j) {
        int rr = g * 4 + j;
        gm[j] = fmaxf(fmaxf(smax[0][rr], smax[1][rr]),
                      fmaxf(smax[2][rr], smax[3][rr]));
    }

    float rsum[4] = {0.f, 0.f, 0.f, 0.f};
#pragma unroll
    for (int t = 0; t < 16; ++t)
#pragma unroll
        for (int j = 0; j < 4; ++j) {
            float e = __expf(p[t][j] - gm[j]);
            p[t][j] = e;
            rsum[j] += e;
        }
#pragma unroll
    for (int j = 0; j < 4; ++j)
#pragma unroll
        for (int m = 1; m < 16; m <<= 1)
            rsum[j] += __shfl_xor(rsum[j], m, 64);
    if (r16 == 0) {
#pragma unroll
        for (int j = 0; j < 4; ++j) ssum[w][g * 4 + j] = rsum[j];
    }
    __syncthreads();
    float inv[4];
#pragma unroll
    for (int j = 0; j < 4; ++j) {
        int rr = g * 4 + j;
        inv[j] = 1.0f / (ssum[0][rr] + ssum[1][rr] + ssum[2][rr] + ssum[3][rr]);
    }

    float* abase = attn + ((size_t)bh * N_ + n0 + 4 * g) * N_ + w * 256 + r16;
#pragma unroll
    for (int j = 0; j < 4; ++j) {
        float* arow = abase + (size_t)j * N_;
        float sc = inv[j];
#pragma unroll
        for (int t = 0; t < 16; ++t)
            arow[t * 16] = p[t][j] * sc;
    }
}

// ---------------------------------------------------------------------------
// Kernel 3: pv_gemm (unchanged)
// ---------------------------------------------------------------------------
__global__ __launch_bounds__(256) void pv_gemm(const float* __restrict__ qkv,
                                               const float* __restrict__ attn,
                                               float* __restrict__ ctx) {
    __shared__ __align__(16) float Pst[64][68];   // [m][n]  (transposed P)
    __shared__ __align__(16) float Vs[64][68];    // [m][d]

    const int tid = threadIdx.x;
    const int tx = tid & 15;          // d-group
    const int ty = tid >> 4;          // n-group
    const int n0 = blockIdx.x * 64;
    const int bh = blockIdx.y;
    const int b = bh >> 3, h = bh & 7;
    const size_t RS = 3 * C_;

    const int rr = tid >> 2;          // staging row 0..63
    const int q = tid & 3;            // staging quarter

    float acc[4][4] = {};

    for (int mt = 0; mt < 16; ++mt) {
        const int m0 = mt * 64;
        const float* prow = attn + ((size_t)bh * N_ + n0 + rr) * N_ + m0 + q * 16;
        const float* vrow = qkv + (size_t)(b * N_ + m0 + rr) * RS + 2 * C_ + h * HD_ + q * 16;
        float4 pv[4], vv[4];
#pragma unroll
        for (int m = 0; m < 4; ++m) pv[m] = ((const float4*)prow)[m];
#pragma unroll
        for (int m = 0; m < 4; ++m) vv[m] = ((const float4*)vrow)[m];
        __syncthreads();
#pragma unroll
        for (int m = 0; m < 4; ++m) {
            int c = q * 16 + m * 4;
            Pst[c + 0][rr] = pv[m].x; Pst[c + 1][rr] = pv[m].y;
            Pst[c + 2][rr] = pv[m].z; Pst[c + 3][rr] = pv[m].w;
            *(float4*)&Vs[rr][c] = vv[m];
        }
        __syncthreads();
#pragma unroll 16
        for (int mm = 0; mm < 64; ++mm) {
            float4 a4 = *(const float4*)&Pst[mm][ty * 4];
            float4 b4 = *(const float4*)&Vs[mm][tx * 4];
            float a[4] = {a4.x, a4.y, a4.z, a4.w};
            float bb[4] = {b4.x, b4.y, b4.z, b4.w};
#pragma unroll
            for (int i = 0; i < 4; ++i)
#pragma unroll
                for (int j = 0; j < 4; ++j) acc[i][j] += a[i] * bb[j];
        }
    }
#pragma unroll
    for (int i = 0; i < 4; ++i) {
        float4 o;
        o.x = acc[i][0]; o.y = acc[i][1]; o.z = acc[i][2]; o.w = acc[i][3];
        *(float4*)&ctx[(size_t)(b * N_ + n0 + ty * 4 + i) * C_ + h * HD_ + tx * 4] = o;
    }
}

// ---------------------------------------------------------------------------
// Kernel 4: proj_gemm — y_pre = ctx @ Wproj + bproj + x  (unchanged)
// ---------------------------------------------------------------------------
__global__ __launch_bounds__(256) void proj_gemm(const float* __restrict__ ctx,
                                                 const float* __restrict__ x,
                                                 const float* __restrict__ Wproj,
                                                 const float* __restrict__ bproj,
                                                 float* __restrict__ y) {
    const int K = C_;
    const int NN = C_;
    __shared__ float As[64][17];
    __shared__ float Bs[16][64];

    const int tid = threadIdx.x;
    const int tx = tid & 15;
    const int ty = tid >> 4;
    const int row0 = blockIdx.y * 64;
    const int col0 = blockIdx.x * 64;

    float acc[4][4] = {};

    for (int kt = 0; kt < K; kt += 16) {
        {
            int lin = tid * 4;
            int m = lin >> 4;
            int k = lin & 15;
            float4 a = *(const float4*)&ctx[(size_t)(row0 + m) * K + kt + k];
            As[m][k + 0] = a.x; As[m][k + 1] = a.y;
            As[m][k + 2] = a.z; As[m][k + 3] = a.w;
        }
        {
            int lin = tid * 4;
            int kk = lin >> 6;
            int n = lin & 63;
            *(float4*)&Bs[kk][n] =
                *(const float4*)&Wproj[(size_t)(kt + kk) * NN + col0 + n];
        }
        __syncthreads();
#pragma unroll
        for (int kk = 0; kk < 16; ++kk) {
            float a[4], bb[4];
#pragma unroll
            for (int i = 0; i < 4; ++i) a[i] = As[ty * 4 + i][kk];
#pragma unroll
            for (int j = 0; j < 4; ++j) bb[j] = Bs[kk][tx * 4 + j];
#pragma unroll
            for (int i = 0; i < 4; ++i)
#pragma unroll
                for (int j = 0; j < 4; ++j) acc[i][j] += a[i] * bb[j];
        }
        __syncthreads();
    }
#pragma unroll
    for (int i = 0; i < 4; ++i) {
        int r = row0 + ty * 4 + i;
        int c = col0 + tx * 4;
        float4 xr = *(const float4*)&x[(size_t)r * C_ + c];
        float4 o;
        o.x = acc[i][0] + bproj[c + 0] + xr.x;
        o.y = acc[i][1] + bproj[c + 1] + xr.y;
        o.z = acc[i][2] + bproj[c + 2] + xr.z;
        o.w = acc[i][3] + bproj[c + 3] + xr.w;
        *(float4*)&y[(size_t)r * C_ + c] = o;
    }
}

// ---------------------------------------------------------------------------
// Kernel 5: ln_kernel (unchanged)
// ---------------------------------------------------------------------------
__global__ __launch_bounds__(256) void ln_kernel(float* __restrict__ y,
                                                 const float* __restrict__ gamma,
                                                 const float* __restrict__ beta) {
    __shared__ float wsum[4], wsq[4];
    const int row = blockIdx.x;
    const int tid = threadIdx.x;
    const int lane = tid & 63;
    const int w = tid >> 6;

    float2 v = ((const float2*)(y + (size_t)row * C_))[tid];
    float s = v.x + v.y;
    float sq = v.x * v.x + v.y * v.y;
#pragma unroll
    for (int m = 1; m < 64; m <<= 1) {
        s += __shfl_xor(s, m, 64);
        sq += __shfl_xor(sq, m, 64);
    }
    if (lane == 0) { wsum[w] = s; wsq[w] = sq; }
    __syncthreads();
    float ts = wsum[0] + wsum[1] + wsum[2] + wsum[3];
    float tq = wsq[0] + wsq[1] + wsq[2] + wsq[3];
    float mu = ts * (1.0f / C_);
    float var = tq * (1.0f / C_) - mu * mu;
    float rstd = rsqrtf(var + LN_EPS_);

    float2 g = ((const float2*)gamma)[tid];
    float2 be = ((const float2*)beta)[tid];
    float2 o;
    o.x = (v.x - mu) * rstd * g.x + be.x;
    o.y = (v.y - mu) * rstd * g.y + be.y;
    ((float2*)(y + (size_t)row * C_))[tid] = o;
}

extern "C" void kernel_launch(void* const* d_in, const int* in_sizes, int n_in,
                              void* d_out, int out_size, void* d_ws, size_t ws_size,
                              hipStream_t stream) {
    const float* x     = (const float*)d_in[0];
    const float* Wqkv  = (const float*)d_in[1];
    const float* bqkv  = (const float*)d_in[2];
    const float* ow    = (const float*)d_in[3];
    const float* Wproj = (const float*)d_in[4];
    const float* bproj = (const float*)d_in[5];
    const float* gamma = (const float*)d_in[6];
    const float* beta  = (const float*)d_in[7];

    float* out  = (float*)d_out;
    float* y    = out;                                  // [B,N,C]
    float* attn = out + (size_t)B_ * N_ * C_;           // [B,H,N,N]
    float* qkv  = (float*)d_ws;                         // [B*N, 3C]  25 MB
    float* ctx  = qkv + (size_t)B_ * N_ * 3 * C_;       // [B*N, C]    8 MB

    // Wt_hi/Wt_lo overlay the attn output region (3 MB of 128 MB); the region
    // is consumed by qkv_gemm_mfma and then fully rewritten by attn_scores.
    _Float16* wt_hi = (_Float16*)attn;
    _Float16* wt_lo = wt_hi + (size_t)(3 * C_) * C_;

    dim3 g0(3 * C_ / 64, C_ / 64);                      // (24, 8)
    wsplit_qkv<<<g0, 256, 0, stream>>>(Wqkv, wt_hi, wt_lo);

    dim3 g1(B_ * N_ / 32, 3 * C_ / 256);                // (128, 6)
    qkv_gemm_mfma<<<g1, 256, 0, stream>>>(x, wt_hi, wt_lo, bqkv, qkv);

    dim3 g2(N_ / 16, B_ * H_);                          // (64, 32)
    attn_scores<<<g2, 256, 0, stream>>>(qkv, ow, attn);

    dim3 g3(N_ / 64, B_ * H_);                          // (16, 32)
    pv_gemm<<<g3, 256, 0, stream>>>(qkv, attn, ctx);

    dim3 g4(C_ / 64, B_ * N_ / 64);                     // (8, 64)
    proj_gemm<<<g4, 256, 0, stream>>>(ctx, x, Wproj, bproj, y);

    ln_kernel<<<B_ * N_, 256, 0, stream>>>(y, gamma, beta);
}